// Round 1
// baseline (1147.348 us; speedup 1.0000x reference)
//
#include <hip/hip_runtime.h>
#include <hip/hip_bf16.h>

// Sizes fixed by the problem
#define BATCH 4
#define TLEN  4096
#define DDIM  1024
#define NCOND 512
#define LDIM  768
#define NHEAD 8
#define HD    128

// ---------------- row stats (mean, rstd) ----------------
__global__ __launch_bounds__(256) void rowstats(const float* __restrict__ x,
                                                float* __restrict__ st, int rowlen) {
    long r = blockIdx.x;
    const float* p = x + r * (long)rowlen;
    int tid = threadIdx.x;
    float s = 0.f, ss = 0.f;
    for (int i = tid; i < rowlen; i += 256) { float v = p[i]; s += v; ss += v * v; }
    for (int off = 32; off; off >>= 1) {
        s  += __shfl_xor(s,  off, 64);
        ss += __shfl_xor(ss, off, 64);
    }
    __shared__ float sh[8];
    int wid = tid >> 6, lane = tid & 63;
    if (lane == 0) { sh[wid * 2] = s; sh[wid * 2 + 1] = ss; }
    __syncthreads();
    if (tid == 0) {
        float S  = sh[0] + sh[2] + sh[4] + sh[6];
        float SS = sh[1] + sh[3] + sh[5] + sh[7];
        float mu = S / rowlen;
        float var = SS / rowlen - mu * mu;
        st[r * 2]     = mu;
        st[r * 2 + 1] = rsqrtf(fmaxf(var, 0.f) + 1e-5f);
    }
}

// ---------------- generic tiled fp32 GEMM with optional LN-on-A and bias ---------
// C[m,n] = sum_k LN(A[m,k]) * B[k,n] + bias[n]
// LN(A[m,k]) = (A[m,k]-mean[m])*rstd[m]*cg[k]+cb[k] when stats/cg non-null.
// z-slicing: offsets = (z/zdiv)*outer + (z%zdiv)*inner for A/B/C.
#define BM 128
#define BN 128
#define BKK 16

__global__ __launch_bounds__(256) void gemm_ln(
    const float* __restrict__ A, int lda,
    const float* __restrict__ stats,
    const float* __restrict__ cg, const float* __restrict__ cbv,
    const float* __restrict__ Bmat, int ldb,
    const float* __restrict__ bias,
    float* __restrict__ C, int ldc,
    int K, int zdiv,
    long long Ao, long long Ai, long long Bo, long long Bi, long long Co, long long Ci)
{
    int zo = blockIdx.z / zdiv, zi = blockIdx.z % zdiv;
    A    += zo * Ao + zi * Ai;
    Bmat += zo * Bo + zi * Bi;
    C    += zo * Co + zi * Ci;

    int m0 = blockIdx.y * BM, n0 = blockIdx.x * BN;
    int tid = threadIdx.x;
    int tx = tid & 15, ty = tid >> 4;

    __shared__ float As[BKK][BM + 4];
    __shared__ float Bs[BKK][BN + 4];

    float acc[8][8];
#pragma unroll
    for (int i = 0; i < 8; i++)
#pragma unroll
        for (int j = 0; j < 8; j++) acc[i][j] = 0.f;

    // A-tile load mapping: thread loads rows am, am+64; cols ak0..ak0+3
    int ak0 = (tid & 3) * 4;
    int am  = tid >> 2;     // 0..63
    // B-tile load mapping
    int bk_ = tid >> 4;         // 0..15
    int bn  = (tid & 15) * 8;   // 0..120

    // hoist per-row LN stats (rows fixed across K loop)
    float mu0 = 0.f, rs0 = 1.f, mu1 = 0.f, rs1 = 1.f;
    if (stats) {
        long r0 = m0 + am, r1 = m0 + am + 64;
        mu0 = stats[r0 * 2]; rs0 = stats[r0 * 2 + 1];
        mu1 = stats[r1 * 2]; rs1 = stats[r1 * 2 + 1];
    }

    for (int kt = 0; kt < K; kt += BKK) {
        // ---- stage A (128x16, transposed into As[k][m]) ----
#pragma unroll
        for (int half = 0; half < 2; half++) {
            int mm = am + half * 64;
            long row = m0 + mm;
            const float4 av = *(const float4*)(A + row * (long)lda + kt + ak0);
            float vals[4] = {av.x, av.y, av.z, av.w};
            if (stats) {
                float mu = half ? mu1 : mu0, rs = half ? rs1 : rs0;
#pragma unroll
                for (int j = 0; j < 4; j++) vals[j] = (vals[j] - mu) * rs;
            }
            if (cg) {
#pragma unroll
                for (int j = 0; j < 4; j++)
                    vals[j] = vals[j] * cg[kt + ak0 + j] + cbv[kt + ak0 + j];
            }
#pragma unroll
            for (int j = 0; j < 4; j++) As[ak0 + j][mm] = vals[j];
        }
        // ---- stage B (16x128) ----
        {
            const float* bp = Bmat + (long)(kt + bk_) * ldb + n0 + bn;
            *(float4*)&Bs[bk_][bn]     = *(const float4*)bp;
            *(float4*)&Bs[bk_][bn + 4] = *(const float4*)(bp + 4);
        }
        __syncthreads();

#pragma unroll
        for (int kk = 0; kk < BKK; kk++) {
            float a[8], b[8];
#pragma unroll
            for (int i = 0; i < 8; i++) a[i] = As[kk][ty * 8 + i];
#pragma unroll
            for (int j = 0; j < 8; j++) b[j] = Bs[kk][tx * 8 + j];
#pragma unroll
            for (int i = 0; i < 8; i++)
#pragma unroll
                for (int j = 0; j < 8; j++) acc[i][j] += a[i] * b[j];
        }
        __syncthreads();
    }

    // ---- epilogue ----
#pragma unroll
    for (int i = 0; i < 8; i++) {
        long row = m0 + ty * 8 + i;
        float* cp = C + row * (long)ldc + n0 + tx * 8;
#pragma unroll
        for (int j = 0; j < 8; j++) {
            float val = acc[i][j];
            if (bias) val += bias[n0 + tx * 8 + j];
            cp[j] = val;
        }
    }
}

// ---------------- softmax over N axis (k), in place ----------------
// k layout [B, N=512, D=1024]; softmax over n for each (b, d) column.
__global__ __launch_bounds__(256) void softmax_n(float* __restrict__ k) {
    int col = blockIdx.x * 256 + threadIdx.x;   // 0..4095
    int b = col >> 10, d = col & 1023;
    float* p = k + (long)b * NCOND * DDIM + d;
    float m = -1e30f, s = 0.f;
#pragma unroll 4
    for (int n = 0; n < NCOND; n++) {
        float v = p[(long)n * DDIM];
        float nm = fmaxf(m, v);
        s = s * __expf(m - nm) + __expf(v - nm);
        m = nm;
    }
    float inv = 1.f / s;
#pragma unroll 4
    for (int n = 0; n < NCOND; n++) {
        float v = p[(long)n * DDIM];
        p[(long)n * DDIM] = __expf(v - m) * inv;
    }
}

// ---------------- context[b,h,kk,vv] = sum_n ksm[b,n,h,kk]*v[b,n,h,vv] -------
// grid.x = B*H*8 strips; each strip = 128 rows(kk) x 16 cols(vv).
#define NC 64
__global__ __launch_bounds__(256) void context_kernel(const float* __restrict__ k,
                                                      const float* __restrict__ v,
                                                      float* __restrict__ ctx) {
    int blk = blockIdx.x;
    int strip = blk & 7;
    int bh = blk >> 3;          // 0..31
    int b = bh >> 3, h = bh & 7;
    int c0 = strip * 16;

    __shared__ float kch[NC][128];
    __shared__ float vch[NC][16];

    int tid = threadIdx.x;
    int r = tid & 127;
    int cb = (tid >> 7) * 8;

    float acc[8];
#pragma unroll
    for (int j = 0; j < 8; j++) acc[j] = 0.f;

    const float* kbase = k + (long)b * NCOND * DDIM + h * HD;
    const float* vbase = v + (long)b * NCOND * DDIM + h * HD + c0;

    for (int n0 = 0; n0 < NCOND; n0 += NC) {
#pragma unroll
        for (int i = 0; i < (NC * 128) / 256; i++) {
            int e = tid + i * 256;
            int nn = e >> 7, col = e & 127;
            kch[nn][col] = kbase[(long)(n0 + nn) * DDIM + col];
        }
#pragma unroll
        for (int i = 0; i < (NC * 16) / 256; i++) {
            int e = tid + i * 256;
            int nn = e >> 4, col = e & 15;
            vch[nn][col] = vbase[(long)(n0 + nn) * DDIM + col];
        }
        __syncthreads();
#pragma unroll 8
        for (int nn = 0; nn < NC; nn++) {
            float kv = kch[nn][r];
#pragma unroll
            for (int j = 0; j < 8; j++) acc[j] += kv * vch[nn][cb + j];
        }
        __syncthreads();
    }
    float* cp = ctx + ((long)bh * 128 + r) * 128 + c0 + cb;
#pragma unroll
    for (int j = 0; j < 8; j++) cp[j] = acc[j];
}

// ---------------- softmax over head dim (128 contiguous), in place ----------
// one wave per 128-element segment; 4 waves per block.
__global__ __launch_bounds__(256) void softmax_head(float* __restrict__ q) {
    long wave = (long)blockIdx.x * 4 + (threadIdx.x >> 6);
    int lane = threadIdx.x & 63;
    float* p = q + wave * 128;
    float v0 = p[lane], v1 = p[lane + 64];
    float m = fmaxf(v0, v1);
#pragma unroll
    for (int off = 32; off; off >>= 1) m = fmaxf(m, __shfl_xor(m, off, 64));
    float e0 = __expf(v0 - m), e1 = __expf(v1 - m);
    float s = e0 + e1;
#pragma unroll
    for (int off = 32; off; off >>= 1) s += __shfl_xor(s, off, 64);
    float inv = 1.f / s;
    p[lane]      = e0 * inv;
    p[lane + 64] = e1 * inv;
}

extern "C" void kernel_launch(void* const* d_in, const int* in_sizes, int n_in,
                              void* d_out, int out_size, void* d_ws, size_t ws_size,
                              hipStream_t stream) {
    (void)in_sizes; (void)n_in; (void)out_size; (void)ws_size;
    const float* x     = (const float*)d_in[0];
    const float* cond  = (const float*)d_in[1];
    const float* ln_g  = (const float*)d_in[2];
    const float* ln_b  = (const float*)d_in[3];
    const float* tln_g = (const float*)d_in[4];
    const float* tln_b = (const float*)d_in[5];
    const float* Wq    = (const float*)d_in[6];
    const float* bq    = (const float*)d_in[7];
    const float* Wk    = (const float*)d_in[8];
    const float* bk    = (const float*)d_in[9];
    const float* Wv    = (const float*)d_in[10];
    const float* bv    = (const float*)d_in[11];
    float* out = (float*)d_out;

    float* ws    = (float*)d_ws;
    float* cstat = ws;                    // 2048*2
    float* xstat = cstat + 4096;          // 16384*2
    float* fk    = xstat + 32768;         // 4*512*1024
    float* fv    = fk + 2097152;          // 4*512*1024
    float* fctx  = fv + 2097152;          // 4*8*128*128
    float* fq    = fctx + 524288;         // 4*4096*1024

    rowstats<<<16384, 256, 0, stream>>>(x, xstat, DDIM);
    rowstats<<<2048, 256, 0, stream>>>(cond, cstat, LDIM);

    // k = LN(cond) @ Wk + bk ; v = LN(cond) @ Wv + bv   (M=2048, K=768, N=1024)
    gemm_ln<<<dim3(8, 16, 1), 256, 0, stream>>>(cond, LDIM, cstat, tln_g, tln_b,
        Wk, DDIM, bk, fk, DDIM, LDIM, 1, 0, 0, 0, 0, 0, 0);
    gemm_ln<<<dim3(8, 16, 1), 256, 0, stream>>>(cond, LDIM, cstat, tln_g, tln_b,
        Wv, DDIM, bv, fv, DDIM, LDIM, 1, 0, 0, 0, 0, 0, 0);

    softmax_n<<<16, 256, 0, stream>>>(fk);
    context_kernel<<<BATCH * NHEAD * 8, 256, 0, stream>>>(fk, fv, fctx);

    // q = LN(x) @ Wq + bq   (M=16384, K=1024, N=1024)
    gemm_ln<<<dim3(8, 128, 1), 256, 0, stream>>>(x, DDIM, xstat, ln_g, ln_b,
        Wq, DDIM, bq, fq, DDIM, DDIM, 1, 0, 0, 0, 0, 0, 0);

    softmax_head<<<(BATCH * TLEN * NHEAD) / 4, 256, 0, stream>>>(fq);

    // y[b,h] = q_sm[b,:,h] @ ctx[b,h]   (per slice: M=4096, K=128, N=128)
    gemm_ln<<<dim3(1, 32, 32), 256, 0, stream>>>(fq, DDIM, nullptr, nullptr, nullptr,
        fctx, HD, nullptr, out, DDIM, HD, NHEAD,
        (long long)TLEN * DDIM, 128LL,
        (long long)NHEAD * HD * HD, (long long)HD * HD,
        (long long)TLEN * DDIM, 128LL);
}

// Round 2
// 342.648 us; speedup vs baseline: 3.3485x; 3.3485x over previous
//
#include <hip/hip_runtime.h>
#include <hip/hip_bf16.h>
#include <stdint.h>

#define BATCH 4
#define TLEN  4096
#define DDIM  1024
#define NCOND 512
#define LDIM  768
#define NHEAD 8
#define HD    128

typedef __bf16 bf16x8 __attribute__((ext_vector_type(8)));
typedef float  f32x4  __attribute__((ext_vector_type(4)));

__device__ __forceinline__ unsigned short f2b(float f) {
    unsigned int u = __builtin_bit_cast(unsigned int, f);
    unsigned int r = (u + 0x7fffu + ((u >> 16) & 1u)) >> 16;
    return (unsigned short)r;
}
__device__ __forceinline__ float b2f(unsigned short s) {
    unsigned int u = ((unsigned int)s) << 16;
    return __builtin_bit_cast(float, u);
}

// async global->LDS, 16B per lane. lds ptr must be wave-uniform base;
// HW adds lane*16. Bit-cast via uintptr_t (LDS generic low-32 == as3 offset).
__device__ __forceinline__ void gl2lds(const void* g, void* l) {
    __builtin_amdgcn_global_load_lds(
        (const __attribute__((address_space(1))) void*)(uintptr_t)g,
        (__attribute__((address_space(3))) void*)(uintptr_t)l,
        16, 0, 0);
}

// ---------------- fused LN stats + apply -> bf16 ----------------
__global__ __launch_bounds__(256) void ln_apply(const float* __restrict__ x,
    const float* __restrict__ g, const float* __restrict__ bb,
    unsigned short* __restrict__ o, int rowlen)
{
    long r = blockIdx.x;
    const float* p = x + r * (long)rowlen;
    int tid = threadIdx.x;
    int c = tid * 4;
    float4 v = make_float4(0.f, 0.f, 0.f, 0.f);
    bool act = c < rowlen;
    if (act) v = *(const float4*)(p + c);
    float s  = v.x + v.y + v.z + v.w;
    float ss = v.x * v.x + v.y * v.y + v.z * v.z + v.w * v.w;
#pragma unroll
    for (int off = 32; off; off >>= 1) {
        s  += __shfl_xor(s,  off, 64);
        ss += __shfl_xor(ss, off, 64);
    }
    __shared__ float sh[8];
    __shared__ float mu_s, rs_s;
    int wid = tid >> 6, lane = tid & 63;
    if (lane == 0) { sh[wid * 2] = s; sh[wid * 2 + 1] = ss; }
    __syncthreads();
    if (tid == 0) {
        float S  = sh[0] + sh[2] + sh[4] + sh[6];
        float SS = sh[1] + sh[3] + sh[5] + sh[7];
        float mu = S / rowlen;
        float var = SS / rowlen - mu * mu;
        mu_s = mu; rs_s = rsqrtf(fmaxf(var, 0.f) + 1e-5f);
    }
    __syncthreads();
    if (act) {
        float mu = mu_s, rs = rs_s;
        float4 gv = *(const float4*)(g + c);
        float4 bv = *(const float4*)(bb + c);
        ushort4 o4;
        o4.x = f2b((v.x - mu) * rs * gv.x + bv.x);
        o4.y = f2b((v.y - mu) * rs * gv.y + bv.y);
        o4.z = f2b((v.z - mu) * rs * gv.z + bv.z);
        o4.w = f2b((v.w - mu) * rs * gv.w + bv.w);
        *(ushort4*)(o + r * (long)rowlen + c) = o4;
    }
}

// ---------------- W [K,N] f32 -> Wt [N,K] bf16 ----------------
__global__ __launch_bounds__(256) void wtrans(const float* __restrict__ W, int K, int N,
                                              unsigned short* __restrict__ Wt)
{
    __shared__ float t[32][33];
    int n0 = blockIdx.x * 32, k0 = blockIdx.y * 32;
    int tx = threadIdx.x & 31, ty = threadIdx.x >> 5;   // ty 0..7
#pragma unroll
    for (int i = 0; i < 4; i++)
        t[ty + i * 8][tx] = W[(long)(k0 + ty + i * 8) * N + n0 + tx];
    __syncthreads();
#pragma unroll
    for (int i = 0; i < 4; i++)
        Wt[(long)(n0 + ty + i * 8) * K + k0 + tx] = f2b(t[tx][ty + i * 8]);
}

// ---------------- bf16 MFMA GEMM (m97 structure) ----------------
// C[m,n] = sum_k A[m,k]*Bt[n,k] + bias[n].  A:[M,K] bf16, Bt:[N,K] bf16.
// 128x128 tile, BK=32, 4 waves 2x2, 16x16x32 MFMA, global_load_lds x16.
template <bool OBF>
__global__ __launch_bounds__(256) void gemm_bf16(
    const unsigned short* __restrict__ A, int lda,
    const unsigned short* __restrict__ Bt, int ldb,
    const float* __restrict__ bias0, const float* __restrict__ bias1,
    void* __restrict__ Cv, int ldc, int K, int zdiv,
    long long Ao, long long Ai, long long Bo, long long Bi,
    long long Co, long long Ci)
{
    int zo = blockIdx.z / zdiv, zi = blockIdx.z % zdiv;
    const unsigned short* Ap = A  + zo * Ao + zi * Ai;
    const unsigned short* Bp = Bt + zo * Bo + zi * Bi;
    const float* bias = (zi & 1) ? bias1 : bias0;
    long coff = zo * Co + zi * Ci;

    int m0 = blockIdx.y * 128, n0 = blockIdx.x * 128;
    int tid = threadIdx.x, lane = tid & 63, wid = tid >> 6;
    int l16 = lane & 15, quad = lane >> 4;
    int mw = (wid & 1) << 6, nw = (wid >> 1) << 6;

    __shared__ unsigned short As[128 * 32];
    __shared__ unsigned short Bs[128 * 32];

    f32x4 acc[4][4];
#pragma unroll
    for (int i = 0; i < 4; i++)
#pragma unroll
        for (int j = 0; j < 4; j++) { acc[i][j][0] = 0.f; acc[i][j][1] = 0.f; acc[i][j][2] = 0.f; acc[i][j][3] = 0.f; }

    const unsigned short* ag = Ap + (long)(m0 + (tid >> 2)) * lda + (tid & 3) * 8;
    const unsigned short* bg = Bp + (long)(n0 + (tid >> 2)) * ldb + (tid & 3) * 8;
    unsigned short* asw = As + wid * 512;   // wave-uniform chunk base
    unsigned short* bsw = Bs + wid * 512;
    long a64 = (long)64 * lda, b64 = (long)64 * ldb;

    for (int kt = 0; kt < K; kt += 32) {
        gl2lds(ag + kt,        asw);
        gl2lds(ag + a64 + kt,  asw + 2048);
        gl2lds(bg + kt,        bsw);
        gl2lds(bg + b64 + kt,  bsw + 2048);
        __syncthreads();
        bf16x8 af[4], bfr[4];
#pragma unroll
        for (int i = 0; i < 4; i++)
            af[i] = *(const bf16x8*)&As[(mw + i * 16 + l16) * 32 + quad * 8];
#pragma unroll
        for (int j = 0; j < 4; j++)
            bfr[j] = *(const bf16x8*)&Bs[(nw + j * 16 + l16) * 32 + quad * 8];
#pragma unroll
        for (int i = 0; i < 4; i++)
#pragma unroll
            for (int j = 0; j < 4; j++)
                acc[i][j] = __builtin_amdgcn_mfma_f32_16x16x32_bf16(af[i], bfr[j], acc[i][j], 0, 0, 0);
        __syncthreads();
    }

#pragma unroll
    for (int j = 0; j < 4; j++) {
        int col = n0 + nw + j * 16 + l16;
        float bvv = bias ? bias[col] : 0.f;
#pragma unroll
        for (int i = 0; i < 4; i++) {
            int row0 = m0 + mw + i * 16 + (quad << 2);
#pragma unroll
            for (int r = 0; r < 4; r++) {
                float val = acc[i][j][r] + bvv;
                long idx = coff + (long)(row0 + r) * ldc + col;
                if (OBF) ((unsigned short*)Cv)[idx] = f2b(val);
                else     ((float*)Cv)[idx] = val;
            }
        }
    }
}

// ---------------- softmax over N (k), fp32 in place, 256 blocks ----------
__global__ __launch_bounds__(256) void softmax_n2(float* __restrict__ k) {
    int d0 = blockIdx.x * 16;          // over B*D = 4096 columns
    int b = d0 >> 10, d = d0 & 1023;
    int col = threadIdx.x & 15, seg = threadIdx.x >> 4;   // 16 segs of 32 n
    float* p = k + (long)b * NCOND * DDIM + d + col;
    float m = -1e30f, s = 0.f;
    for (int n = seg * 32; n < seg * 32 + 32; n++) {
        float v = p[(long)n * DDIM];
        float nm = fmaxf(m, v);
        s = s * __expf(m - nm) + __expf(v - nm);
        m = nm;
    }
    __shared__ float shm[16][17], shs[16][17];
    shm[seg][col] = m; shs[seg][col] = s;
    __syncthreads();
    if (seg == 0) {
        float M = shm[0][col], S = shs[0][col];
#pragma unroll
        for (int t = 1; t < 16; t++) {
            float m2 = shm[t][col], s2 = shs[t][col];
            float nm = fmaxf(M, m2);
            S = S * __expf(M - nm) + s2 * __expf(m2 - nm);
            M = nm;
        }
        shm[0][col] = M; shs[0][col] = S;
    }
    __syncthreads();
    float M = shm[0][col], inv = 1.f / shs[0][col];
    for (int n = seg * 32; n < seg * 32 + 32; n++) {
        float v = p[(long)n * DDIM];
        p[(long)n * DDIM] = __expf(v - M) * inv;
    }
}

// ---------------- ctx_t[b,h,vv,kk] = sum_n k_sm[b,n,h,kk]*v[b,n,h,vv], bf16 out
__global__ __launch_bounds__(256) void context_t(const float* __restrict__ k,
                                                 const float* __restrict__ v,
                                                 unsigned short* __restrict__ ctxT)
{
    int blk = blockIdx.x;
    int strip = blk & 7;           // kk strip (16 wide)
    int bh = blk >> 3;
    int b = bh >> 3, h = bh & 7;
    int c0 = strip * 16;

    __shared__ float vch[64][128];
    __shared__ float kch[64][16];

    int tid = threadIdx.x;
    int r = tid & 127;             // vv
    int cb = (tid >> 7) * 8;       // kk sub-offset

    float acc[8];
#pragma unroll
    for (int j = 0; j < 8; j++) acc[j] = 0.f;

    const float* vbase = v + (long)b * NCOND * DDIM + h * HD;
    const float* kbase = k + (long)b * NCOND * DDIM + h * HD + c0;

    for (int n0 = 0; n0 < NCOND; n0 += 64) {
#pragma unroll
        for (int i = 0; i < 32; i++) {
            int e = tid + i * 256;
            int nn = e >> 7, colv = e & 127;
            vch[nn][colv] = vbase[(long)(n0 + nn) * DDIM + colv];
        }
#pragma unroll
        for (int i = 0; i < 4; i++) {
            int e = tid + i * 256;
            int nn = e >> 4, colk = e & 15;
            kch[nn][colk] = kbase[(long)(n0 + nn) * DDIM + colk];
        }
        __syncthreads();
#pragma unroll 8
        for (int nn = 0; nn < 64; nn++) {
            float vv_ = vch[nn][r];
#pragma unroll
            for (int j = 0; j < 8; j++) acc[j] += vv_ * kch[nn][cb + j];
        }
        __syncthreads();
    }
    unsigned short* cp = ctxT + ((long)bh * 128 + r) * 128 + c0 + cb;
#pragma unroll
    for (int j = 0; j < 8; j++) cp[j] = f2b(acc[j]);
}

// ---------------- softmax over head dim (128), bf16 in place ----------
__global__ __launch_bounds__(256) void softmax_head_bf16(unsigned short* __restrict__ q) {
    long wave = (long)blockIdx.x * 4 + (threadIdx.x >> 6);
    int lane = threadIdx.x & 63;
    unsigned short* p = q + wave * 128;
    float v0 = b2f(p[lane]), v1 = b2f(p[lane + 64]);
    float m = fmaxf(v0, v1);
#pragma unroll
    for (int off = 32; off; off >>= 1) m = fmaxf(m, __shfl_xor(m, off, 64));
    float e0 = __expf(v0 - m), e1 = __expf(v1 - m);
    float s = e0 + e1;
#pragma unroll
    for (int off = 32; off; off >>= 1) s += __shfl_xor(s, off, 64);
    float inv = 1.f / s;
    p[lane]      = f2b(e0 * inv);
    p[lane + 64] = f2b(e1 * inv);
}

extern "C" void kernel_launch(void* const* d_in, const int* in_sizes, int n_in,
                              void* d_out, int out_size, void* d_ws, size_t ws_size,
                              hipStream_t stream) {
    (void)in_sizes; (void)n_in; (void)out_size; (void)ws_size;
    const float* x     = (const float*)d_in[0];
    const float* cond  = (const float*)d_in[1];
    const float* ln_g  = (const float*)d_in[2];
    const float* ln_b  = (const float*)d_in[3];
    const float* tln_g = (const float*)d_in[4];
    const float* tln_b = (const float*)d_in[5];
    const float* Wq    = (const float*)d_in[6];
    const float* bq    = (const float*)d_in[7];
    const float* Wk    = (const float*)d_in[8];
    const float* bk    = (const float*)d_in[9];
    const float* Wv    = (const float*)d_in[10];
    const float* bv    = (const float*)d_in[11];
    float* out = (float*)d_out;

    uint8_t* w8 = (uint8_t*)d_ws;
    unsigned short* xn   = (unsigned short*)w8;                  // 33,554,432 B
    unsigned short* cn   = (unsigned short*)(w8 + 33554432);     //  3,145,728
    unsigned short* wqT  = (unsigned short*)(w8 + 36700160);     //  2,097,152
    unsigned short* wkvT = (unsigned short*)(w8 + 38797312);     //  3,145,728
    unsigned short* fqb  = (unsigned short*)(w8 + 41943040);     // 33,554,432
    float*          fk   = (float*)(w8 + 75497472);              //  8,388,608
    float*          fv   = (float*)(w8 + 83886080);              //  8,388,608
    unsigned short* ctxT = (unsigned short*)(w8 + 92274688);     //  1,048,576

    ln_apply<<<16384, 256, 0, stream>>>(x, ln_g, ln_b, xn, DDIM);
    ln_apply<<<2048, 256, 0, stream>>>(cond, tln_g, tln_b, cn, LDIM);

    wtrans<<<dim3(32, 32), 256, 0, stream>>>(Wq, DDIM, DDIM, wqT);
    wtrans<<<dim3(32, 24), 256, 0, stream>>>(Wk, LDIM, DDIM, wkvT);
    wtrans<<<dim3(32, 24), 256, 0, stream>>>(Wv, LDIM, DDIM, wkvT + 768 * 1024);

    // q = LN(x) @ Wq + bq  -> bf16   (M=16384, K=1024, N=1024)
    gemm_bf16<true><<<dim3(8, 128, 1), 256, 0, stream>>>(
        xn, DDIM, wqT, DDIM, bq, bq, fqb, DDIM, DDIM, 1,
        0, 0, 0, 0, 0, 0);

    // k,v = LN(cond) @ {Wk,Wv} + {bk,bv} -> f32  (M=2048, K=768, N=1024, fused z)
    gemm_bf16<false><<<dim3(8, 16, 2), 256, 0, stream>>>(
        cn, LDIM, wkvT, LDIM, bk, bv, fk, DDIM, LDIM, 2,
        0, 0, 0, (long long)768 * 1024, 0, 2097152LL);

    softmax_n2<<<256, 256, 0, stream>>>(fk);
    context_t<<<256, 256, 0, stream>>>(fk, fv, ctxT);
    softmax_head_bf16<<<(BATCH * TLEN * NHEAD) / 4, 256, 0, stream>>>(fqb);

    // y[b,:,h] = q_sm[b,:,h] @ ctx[b,h]^T  (per slice M=4096, K=128, N=128)
    gemm_bf16<false><<<dim3(1, 32, 32), 256, 0, stream>>>(
        fqb, DDIM, ctxT, HD, nullptr, nullptr, out, DDIM, HD, 8,
        (long long)TLEN * DDIM, 128LL, 131072LL, 16384LL,
        (long long)TLEN * DDIM, 128LL);
}

// Round 3
// 291.262 us; speedup vs baseline: 3.9392x; 1.1764x over previous
//
#include <hip/hip_runtime.h>
#include <hip/hip_bf16.h>
#include <stdint.h>

#define BATCH 4
#define TLEN  4096
#define DDIM  1024
#define NCOND 512
#define LDIM  768
#define NHEAD 8
#define HD    128

typedef __bf16 bf16x8 __attribute__((ext_vector_type(8)));
typedef float  f32x4  __attribute__((ext_vector_type(4)));

__device__ __forceinline__ unsigned short f2b(float f) {
    unsigned int u = __builtin_bit_cast(unsigned int, f);
    unsigned int r = (u + 0x7fffu + ((u >> 16) & 1u)) >> 16;
    return (unsigned short)r;
}
__device__ __forceinline__ float b2f(unsigned short s) {
    unsigned int u = ((unsigned int)s) << 16;
    return __builtin_bit_cast(float, u);
}

__device__ __forceinline__ void gl2lds(const void* g, void* l) {
    __builtin_amdgcn_global_load_lds(
        (const __attribute__((address_space(1))) void*)(uintptr_t)g,
        (__attribute__((address_space(3))) void*)(uintptr_t)l,
        16, 0, 0);
}

// ---------------- fused LN stats + apply -> bf16 ----------------
__global__ __launch_bounds__(256) void ln_apply(const float* __restrict__ x,
    const float* __restrict__ g, const float* __restrict__ bb,
    unsigned short* __restrict__ o, int rowlen)
{
    long r = blockIdx.x;
    const float* p = x + r * (long)rowlen;
    int tid = threadIdx.x;
    int c = tid * 4;
    float4 v = make_float4(0.f, 0.f, 0.f, 0.f);
    bool act = c < rowlen;
    if (act) v = *(const float4*)(p + c);
    float s  = v.x + v.y + v.z + v.w;
    float ss = v.x * v.x + v.y * v.y + v.z * v.z + v.w * v.w;
#pragma unroll
    for (int off = 32; off; off >>= 1) {
        s  += __shfl_xor(s,  off, 64);
        ss += __shfl_xor(ss, off, 64);
    }
    __shared__ float sh[8];
    __shared__ float mu_s, rs_s;
    int wid = tid >> 6, lane = tid & 63;
    if (lane == 0) { sh[wid * 2] = s; sh[wid * 2 + 1] = ss; }
    __syncthreads();
    if (tid == 0) {
        float S  = sh[0] + sh[2] + sh[4] + sh[6];
        float SS = sh[1] + sh[3] + sh[5] + sh[7];
        float mu = S / rowlen;
        float var = SS / rowlen - mu * mu;
        mu_s = mu; rs_s = rsqrtf(fmaxf(var, 0.f) + 1e-5f);
    }
    __syncthreads();
    if (act) {
        float mu = mu_s, rs = rs_s;
        float4 gv = *(const float4*)(g + c);
        float4 bv = *(const float4*)(bb + c);
        ushort4 o4;
        o4.x = f2b((v.x - mu) * rs * gv.x + bv.x);
        o4.y = f2b((v.y - mu) * rs * gv.y + bv.y);
        o4.z = f2b((v.z - mu) * rs * gv.z + bv.z);
        o4.w = f2b((v.w - mu) * rs * gv.w + bv.w);
        *(ushort4*)(o + r * (long)rowlen + c) = o4;
    }
}

// ---------------- W [K,N] f32 -> Wt [N,K] bf16 ----------------
__global__ __launch_bounds__(256) void wtrans(const float* __restrict__ W, int K, int N,
                                              unsigned short* __restrict__ Wt)
{
    __shared__ float t[32][33];
    int n0 = blockIdx.x * 32, k0 = blockIdx.y * 32;
    int tx = threadIdx.x & 31, ty = threadIdx.x >> 5;
#pragma unroll
    for (int i = 0; i < 4; i++)
        t[ty + i * 8][tx] = W[(long)(k0 + ty + i * 8) * N + n0 + tx];
    __syncthreads();
#pragma unroll
    for (int i = 0; i < 4; i++)
        Wt[(long)(n0 + ty + i * 8) * K + k0 + tx] = f2b(t[tx][ty + i * 8]);
}

// ---------------- bf16 MFMA GEMM (kv projection) ----------------
template <bool OBF>
__global__ __launch_bounds__(256) void gemm_bf16(
    const unsigned short* __restrict__ A, int lda,
    const unsigned short* __restrict__ Bt, int ldb,
    const float* __restrict__ bias0, const float* __restrict__ bias1,
    void* __restrict__ Cv, int ldc, int K, int zdiv,
    long long Ao, long long Ai, long long Bo, long long Bi,
    long long Co, long long Ci)
{
    int zo = blockIdx.z / zdiv, zi = blockIdx.z % zdiv;
    const unsigned short* Ap = A  + zo * Ao + zi * Ai;
    const unsigned short* Bp = Bt + zo * Bo + zi * Bi;
    const float* bias = (zi & 1) ? bias1 : bias0;
    long coff = zo * Co + zi * Ci;

    int m0 = blockIdx.y * 128, n0 = blockIdx.x * 128;
    int tid = threadIdx.x, lane = tid & 63, wid = tid >> 6;
    int l16 = lane & 15, quad = lane >> 4;
    int mw = (wid & 1) << 6, nw = (wid >> 1) << 6;

    __shared__ unsigned short As[128 * 32];
    __shared__ unsigned short Bs[128 * 32];

    f32x4 acc[4][4];
#pragma unroll
    for (int i = 0; i < 4; i++)
#pragma unroll
        for (int j = 0; j < 4; j++) { acc[i][j][0] = 0.f; acc[i][j][1] = 0.f; acc[i][j][2] = 0.f; acc[i][j][3] = 0.f; }

    const unsigned short* ag = Ap + (long)(m0 + (tid >> 2)) * lda + (tid & 3) * 8;
    const unsigned short* bg = Bp + (long)(n0 + (tid >> 2)) * ldb + (tid & 3) * 8;
    unsigned short* asw = As + wid * 512;
    unsigned short* bsw = Bs + wid * 512;
    long a64 = (long)64 * lda, b64 = (long)64 * ldb;

    for (int kt = 0; kt < K; kt += 32) {
        gl2lds(ag + kt,        asw);
        gl2lds(ag + a64 + kt,  asw + 2048);
        gl2lds(bg + kt,        bsw);
        gl2lds(bg + b64 + kt,  bsw + 2048);
        __syncthreads();
        bf16x8 af[4], bfr[4];
#pragma unroll
        for (int i = 0; i < 4; i++)
            af[i] = *(const bf16x8*)&As[(mw + i * 16 + l16) * 32 + quad * 8];
#pragma unroll
        for (int j = 0; j < 4; j++)
            bfr[j] = *(const bf16x8*)&Bs[(nw + j * 16 + l16) * 32 + quad * 8];
#pragma unroll
        for (int i = 0; i < 4; i++)
#pragma unroll
            for (int j = 0; j < 4; j++)
                acc[i][j] = __builtin_amdgcn_mfma_f32_16x16x32_bf16(af[i], bfr[j], acc[i][j], 0, 0, 0);
        __syncthreads();
    }

#pragma unroll
    for (int j = 0; j < 4; j++) {
        int col = n0 + nw + j * 16 + l16;
        float bvv = bias ? bias[col] : 0.f;
#pragma unroll
        for (int i = 0; i < 4; i++) {
            int row0 = m0 + mw + i * 16 + (quad << 2);
#pragma unroll
            for (int r = 0; r < 4; r++) {
                float val = acc[i][j][r] + bvv;
                long idx = coff + (long)(row0 + r) * ldc + col;
                if (OBF) ((unsigned short*)Cv)[idx] = f2b(val);
                else     ((float*)Cv)[idx] = val;
            }
        }
    }
}

// ---------------- fused q-path: proj + bias + head-softmax + @ctx -> out ----
// block: 128 rows (m) x 1 head (128 cols). grid (128 mtiles, 8 heads).
__global__ __launch_bounds__(256) void qfused(
    const unsigned short* __restrict__ xn,   // [16384,1024] bf16
    const unsigned short* __restrict__ wqT,  // [1024,1024]  bf16 (out-major)
    const float* __restrict__ bq,            // [1024]
    const unsigned short* __restrict__ ctxT, // [32][128(vv)][128(kk)] bf16
    float* __restrict__ out)                 // [16384,1024] f32
{
    __shared__ unsigned short buf[35840];        // 71,680 B
    unsigned short* As = buf;                    // 8,192 B   (overlaps Pb)
    unsigned short* Bs = buf + 4096;             // 8,192 B
    unsigned short* Pb = buf;                    // 128*136*2 = 34,816 B
    unsigned short* Cx = buf + 17408;            // 34,816 B
    float* redM = (float*)(buf + 34816);         // [2][128]
    float* redS = redM + 256;                    // [2][128]

    int head = blockIdx.y;
    int m0 = blockIdx.x * 128;
    int b  = m0 >> 12;
    int tid = threadIdx.x, lane = tid & 63, wid = tid >> 6;
    int l16 = lane & 15, quad = lane >> 4;
    int mw = (wid & 1) << 6, nw = (wid >> 1) << 6;
    int ch = wid >> 1;

    // stage ctx tile [128][128] -> Cx [vv][136]
    {
        const unsigned short* cg = ctxT + ((long)(b * NHEAD + head) << 14);
#pragma unroll
        for (int pass = 0; pass < 8; pass++) {
            int idx = pass * 2048 + tid * 8;
            int vv = idx >> 7, kk = idx & 127;
            *(bf16x8*)&Cx[vv * 136 + kk] = *(const bf16x8*)&cg[idx];
        }
    }

    f32x4 acc[4][4];
#pragma unroll
    for (int i = 0; i < 4; i++)
#pragma unroll
        for (int j = 0; j < 4; j++) { acc[i][j][0] = 0.f; acc[i][j][1] = 0.f; acc[i][j][2] = 0.f; acc[i][j][3] = 0.f; }

    const unsigned short* ag = xn  + (long)(m0 + (tid >> 2)) * DDIM + (tid & 3) * 8;
    const unsigned short* bg = wqT + (long)(head * 128 + (tid >> 2)) * DDIM + (tid & 3) * 8;
    unsigned short* asw = As + wid * 512;
    unsigned short* bsw = Bs + wid * 512;
    const long a64 = 64L * DDIM;

    for (int kt = 0; kt < DDIM; kt += 32) {
        gl2lds(ag + kt,        asw);
        gl2lds(ag + a64 + kt,  asw + 2048);
        gl2lds(bg + kt,        bsw);
        gl2lds(bg + a64 + kt,  bsw + 2048);
        __syncthreads();
        bf16x8 af[4], bfr[4];
#pragma unroll
        for (int i = 0; i < 4; i++)
            af[i] = *(const bf16x8*)&As[(mw + i * 16 + l16) * 32 + quad * 8];
#pragma unroll
        for (int j = 0; j < 4; j++)
            bfr[j] = *(const bf16x8*)&Bs[(nw + j * 16 + l16) * 32 + quad * 8];
#pragma unroll
        for (int i = 0; i < 4; i++)
#pragma unroll
            for (int j = 0; j < 4; j++)
                acc[i][j] = __builtin_amdgcn_mfma_f32_16x16x32_bf16(af[i], bfr[j], acc[i][j], 0, 0, 0);
        __syncthreads();
    }

    // ---- bias ----
    float bvv[4];
#pragma unroll
    for (int j = 0; j < 4; j++) bvv[j] = bq[head * 128 + nw + j * 16 + l16];
#pragma unroll
    for (int i = 0; i < 4; i++)
#pragma unroll
        for (int j = 0; j < 4; j++)
#pragma unroll
            for (int r = 0; r < 4; r++) acc[i][j][r] += bvv[j];

    // ---- row max (this wave's 64-col half) ----
    float mx[4][4];
#pragma unroll
    for (int i = 0; i < 4; i++)
#pragma unroll
        for (int r = 0; r < 4; r++) {
            float m = acc[i][0][r];
            m = fmaxf(m, acc[i][1][r]);
            m = fmaxf(m, acc[i][2][r]);
            m = fmaxf(m, acc[i][3][r]);
            mx[i][r] = m;
        }
#pragma unroll
    for (int off = 1; off < 16; off <<= 1)
#pragma unroll
        for (int i = 0; i < 4; i++)
#pragma unroll
            for (int r = 0; r < 4; r++)
                mx[i][r] = fmaxf(mx[i][r], __shfl_xor(mx[i][r], off, 64));
    if (l16 == 0) {
#pragma unroll
        for (int i = 0; i < 4; i++)
#pragma unroll
            for (int r = 0; r < 4; r++)
                redM[ch * 128 + mw + i * 16 + quad * 4 + r] = mx[i][r];
    }
    __syncthreads();

    // ---- exp (bf16-rounded), partial sums, write P to LDS ----
    float sm[4][4];
#pragma unroll
    for (int i = 0; i < 4; i++)
#pragma unroll
        for (int r = 0; r < 4; r++) {
            int row = mw + i * 16 + quad * 4 + r;
            float M = fmaxf(redM[row], redM[128 + row]);
            float s = 0.f;
#pragma unroll
            for (int j = 0; j < 4; j++) {
                unsigned short eb = f2b(__expf(acc[i][j][r] - M));
                Pb[row * 136 + nw + j * 16 + l16] = eb;
                s += b2f(eb);
            }
            sm[i][r] = s;
        }
#pragma unroll
    for (int off = 1; off < 16; off <<= 1)
#pragma unroll
        for (int i = 0; i < 4; i++)
#pragma unroll
            for (int r = 0; r < 4; r++)
                sm[i][r] += __shfl_xor(sm[i][r], off, 64);
    if (l16 == 0) {
#pragma unroll
        for (int i = 0; i < 4; i++)
#pragma unroll
            for (int r = 0; r < 4; r++)
                redS[ch * 128 + mw + i * 16 + quad * 4 + r] = sm[i][r];
    }
    __syncthreads();

    // ---- stage 2: y = P @ ctx^T (K=128) ----
    f32x4 acc2[4][4];
#pragma unroll
    for (int i = 0; i < 4; i++)
#pragma unroll
        for (int j = 0; j < 4; j++) { acc2[i][j][0] = 0.f; acc2[i][j][1] = 0.f; acc2[i][j][2] = 0.f; acc2[i][j][3] = 0.f; }
#pragma unroll
    for (int ks = 0; ks < 4; ks++) {
        bf16x8 af[4], bfr[4];
#pragma unroll
        for (int i = 0; i < 4; i++)
            af[i] = *(const bf16x8*)&Pb[(mw + i * 16 + l16) * 136 + ks * 32 + quad * 8];
#pragma unroll
        for (int j = 0; j < 4; j++)
            bfr[j] = *(const bf16x8*)&Cx[(nw + j * 16 + l16) * 136 + ks * 32 + quad * 8];
#pragma unroll
        for (int i = 0; i < 4; i++)
#pragma unroll
            for (int j = 0; j < 4; j++)
                acc2[i][j] = __builtin_amdgcn_mfma_f32_16x16x32_bf16(af[i], bfr[j], acc2[i][j], 0, 0, 0);
    }

    // ---- epilogue: scale by 1/rowsum, write f32 ----
#pragma unroll
    for (int i = 0; i < 4; i++)
#pragma unroll
        for (int r = 0; r < 4; r++) {
            int row = mw + i * 16 + quad * 4 + r;
            float invd = 1.f / (redS[row] + redS[128 + row]);
            float* op = out + (long)(m0 + row) * DDIM + head * 128;
#pragma unroll
            for (int j = 0; j < 4; j++)
                op[nw + j * 16 + l16] = acc2[i][j][r] * invd;
        }
}

// ---------------- softmax over N (k), fp32 in place ----------
__global__ __launch_bounds__(256) void softmax_n2(float* __restrict__ k) {
    int d0 = blockIdx.x * 16;
    int b = d0 >> 10, d = d0 & 1023;
    int col = threadIdx.x & 15, seg = threadIdx.x >> 4;
    float* p = k + (long)b * NCOND * DDIM + d + col;
    float m = -1e30f, s = 0.f;
    for (int n = seg * 32; n < seg * 32 + 32; n++) {
        float v = p[(long)n * DDIM];
        float nm = fmaxf(m, v);
        s = s * __expf(m - nm) + __expf(v - nm);
        m = nm;
    }
    __shared__ float shm[16][17], shs[16][17];
    shm[seg][col] = m; shs[seg][col] = s;
    __syncthreads();
    if (seg == 0) {
        float M = shm[0][col], S = shs[0][col];
#pragma unroll
        for (int t = 1; t < 16; t++) {
            float m2 = shm[t][col], s2 = shs[t][col];
            float nm = fmaxf(M, m2);
            S = S * __expf(M - nm) + s2 * __expf(m2 - nm);
            M = nm;
        }
        shm[0][col] = M; shs[0][col] = S;
    }
    __syncthreads();
    float M = shm[0][col], inv = 1.f / shs[0][col];
    for (int n = seg * 32; n < seg * 32 + 32; n++) {
        float v = p[(long)n * DDIM];
        p[(long)n * DDIM] = __expf(v - M) * inv;
    }
}

// ---------------- ctx_t[b,h,vv,kk] = sum_n k_sm[b,n,h,kk]*v[b,n,h,vv] -------
__global__ __launch_bounds__(256) void context_t(const float* __restrict__ k,
                                                 const float* __restrict__ v,
                                                 unsigned short* __restrict__ ctxT)
{
    int blk = blockIdx.x;
    int strip = blk & 7;
    int bh = blk >> 3;
    int b = bh >> 3, h = bh & 7;
    int c0 = strip * 16;

    __shared__ float vch[64][128];
    __shared__ float kch[64][16];

    int tid = threadIdx.x;
    int r = tid & 127;
    int cb = (tid >> 7) * 8;

    float acc[8];
#pragma unroll
    for (int j = 0; j < 8; j++) acc[j] = 0.f;

    const float* vbase = v + (long)b * NCOND * DDIM + h * HD;
    const float* kbase = k + (long)b * NCOND * DDIM + h * HD + c0;

    for (int n0 = 0; n0 < NCOND; n0 += 64) {
#pragma unroll
        for (int i = 0; i < 32; i++) {
            int e = tid + i * 256;
            int nn = e >> 7, colv = e & 127;
            vch[nn][colv] = vbase[(long)(n0 + nn) * DDIM + colv];
        }
#pragma unroll
        for (int i = 0; i < 4; i++) {
            int e = tid + i * 256;
            int nn = e >> 4, colk = e & 15;
            kch[nn][colk] = kbase[(long)(n0 + nn) * DDIM + colk];
        }
        __syncthreads();
#pragma unroll 8
        for (int nn = 0; nn < 64; nn++) {
            float vv_ = vch[nn][r];
#pragma unroll
            for (int j = 0; j < 8; j++) acc[j] += vv_ * kch[nn][cb + j];
        }
        __syncthreads();
    }
    unsigned short* cp = ctxT + ((long)bh * 128 + r) * 128 + c0 + cb;
#pragma unroll
    for (int j = 0; j < 8; j++) cp[j] = f2b(acc[j]);
}

extern "C" void kernel_launch(void* const* d_in, const int* in_sizes, int n_in,
                              void* d_out, int out_size, void* d_ws, size_t ws_size,
                              hipStream_t stream) {
    (void)in_sizes; (void)n_in; (void)out_size; (void)ws_size;
    const float* x     = (const float*)d_in[0];
    const float* cond  = (const float*)d_in[1];
    const float* ln_g  = (const float*)d_in[2];
    const float* ln_b  = (const float*)d_in[3];
    const float* tln_g = (const float*)d_in[4];
    const float* tln_b = (const float*)d_in[5];
    const float* Wq    = (const float*)d_in[6];
    const float* bq    = (const float*)d_in[7];
    const float* Wk    = (const float*)d_in[8];
    const float* bk    = (const float*)d_in[9];
    const float* Wv    = (const float*)d_in[10];
    const float* bv    = (const float*)d_in[11];
    float* out = (float*)d_out;

    uint8_t* w8 = (uint8_t*)d_ws;
    unsigned short* xn   = (unsigned short*)w8;                  // 33,554,432 B
    unsigned short* cn   = (unsigned short*)(w8 + 33554432);     //  3,145,728
    unsigned short* wqT  = (unsigned short*)(w8 + 36700160);     //  2,097,152
    unsigned short* wkvT = (unsigned short*)(w8 + 38797312);     //  3,145,728
    float*          fk   = (float*)(w8 + 41943040);              //  8,388,608
    float*          fv   = (float*)(w8 + 50331648);              //  8,388,608
    unsigned short* ctxT = (unsigned short*)(w8 + 58720256);     //  1,048,576

    ln_apply<<<2048, 256, 0, stream>>>(cond, tln_g, tln_b, cn, LDIM);
    wtrans<<<dim3(32, 24), 256, 0, stream>>>(Wk, LDIM, DDIM, wkvT);
    wtrans<<<dim3(32, 24), 256, 0, stream>>>(Wv, LDIM, DDIM, wkvT + 768 * 1024);
    ln_apply<<<16384, 256, 0, stream>>>(x, ln_g, ln_b, xn, DDIM);
    wtrans<<<dim3(32, 32), 256, 0, stream>>>(Wq, DDIM, DDIM, wqT);

    // k,v = LN(cond) @ {Wk,Wv} + {bk,bv} -> f32  (M=2048, K=768, N=1024)
    gemm_bf16<false><<<dim3(8, 16, 2), 256, 0, stream>>>(
        cn, LDIM, wkvT, LDIM, bk, bv, fk, DDIM, LDIM, 2,
        0, 0, 0, (long long)768 * 1024, 0, 2097152LL);

    softmax_n2<<<256, 256, 0, stream>>>(fk);
    context_t<<<256, 256, 0, stream>>>(fk, fv, ctxT);

    // fused: q-proj + softmax + @ctx -> out
    qfused<<<dim3(128, 8), 256, 0, stream>>>(xn, wqT, bq, ctxT, out);
}